// Round 4
// baseline (402.553 us; speedup 1.0000x reference)
//
#include <hip/hip_runtime.h>
#include <math.h>

#define BB 16
#define LL 8192
#define DD 512
#define GG 64   // blocks per batch in pass 1 (128 rows each)

typedef float vf4 __attribute__((ext_vector_type(4)));  // clang-native: OK for nontemporal builtins

__device__ __forceinline__ float dot8v(const vf4& x0, const vf4& x1, const float* qf) {
  return x0.x * qf[0] + x0.y * qf[1] + x0.z * qf[2] + x0.w * qf[3]
       + x1.x * qf[4] + x1.y * qf[5] + x1.z * qf[6] + x1.w * qf[7];
}
__device__ __forceinline__ float dot8(const float4& x0, const float4& x1, const float* qf) {
  return x0.x * qf[0] + x0.y * qf[1] + x0.z * qf[2] + x0.w * qf[3]
       + x1.x * qf[4] + x1.y * qf[5] + x1.z * qf[6] + x1.w * qf[7];
}

// ---------------- Kernel 0: q = query @ W_align^T + b_align ----------------
__global__ __launch_bounds__(512) void qproj_kernel(
    const float* __restrict__ query, const float* __restrict__ Wa,
    const float* __restrict__ ba, float* __restrict__ qout) {
  const int b = blockIdx.x >> 2, chunk = blockIdx.x & 3;
  const int t = threadIdx.x;
  __shared__ float qs[DD];
  qs[t] = query[b * DD + t];
  __syncthreads();
  const int wave = t >> 6, lane = t & 63;
  float qf[8];
#pragma unroll
  for (int j = 0; j < 8; ++j) qf[j] = qs[lane * 8 + j];
  const int d0 = chunk * 128;
  for (int d = d0 + wave; d < d0 + 128; d += 8) {
    const float4* wrow = reinterpret_cast<const float4*>(Wa + (size_t)d * DD + lane * 8);
    float s = dot8(wrow[0], wrow[1], qf);
#pragma unroll
    for (int off = 32; off >= 1; off >>= 1) s += __shfl_xor(s, off, 64);
    if (lane == 0) qout[b * DD + d] = ba[d] + s;
  }
}

// ---------------- Kernel 1: online-softmax streaming pass over value -------
// Grid: BB*GG blocks x 512 threads (8 waves). Each wave owns 16 rows,
// processed 8 at a time: 16x16B nontemporal loads in flight, 8 interleaved
// butterflies, ONE online-softmax rescale per 8 rows. value read ONCE.
__global__ __launch_bounds__(512) void attn_pass1(
    const float* __restrict__ value, const int* __restrict__ mask,
    const float* __restrict__ q, float* __restrict__ pc,
    float* __restrict__ pm, float* __restrict__ pl) {
  const int blk = blockIdx.x;
  const int b = blk / GG, g = blk % GG;
  const int t = threadIdx.x;
  const int wave = t >> 6, lane = t & 63;
  const int l0 = g * 128 + wave * 16;

  float qf[8];
  {
    const float4* qp = reinterpret_cast<const float4*>(q + b * DD + lane * 8);
    float4 q0 = qp[0], q1 = qp[1];
    qf[0] = q0.x; qf[1] = q0.y; qf[2] = q0.z; qf[3] = q0.w;
    qf[4] = q1.x; qf[5] = q1.y; qf[6] = q1.z; qf[7] = q1.w;
  }

  float m = -1e38f, ls = 0.f;
  float c[8] = {0.f, 0.f, 0.f, 0.f, 0.f, 0.f, 0.f, 0.f};
  const float* vb = value + (size_t)b * LL * DD;
  const int* mkp = mask + b * LL;

#pragma unroll 1
  for (int i = 0; i < 16; i += 8) {
    const int l = l0 + i;
    vf4 r[8][2];
#pragma unroll
    for (int j = 0; j < 8; ++j) {
      const vf4* vp = reinterpret_cast<const vf4*>(vb + (size_t)(l + j) * DD + lane * 8);
      r[j][0] = __builtin_nontemporal_load(vp);
      r[j][1] = __builtin_nontemporal_load(vp + 1);
    }
    const int4 mA = *reinterpret_cast<const int4*>(mkp + l);      // l % 8 == 0: 16B-aligned
    const int4 mB = *reinterpret_cast<const int4*>(mkp + l + 4);
    float d[8];
#pragma unroll
    for (int j = 0; j < 8; ++j) d[j] = dot8v(r[j][0], r[j][1], qf);
    // 8 interleaved 6-deep butterflies
#pragma unroll
    for (int off = 32; off >= 1; off >>= 1) {
#pragma unroll
      for (int j = 0; j < 8; ++j) d[j] += __shfl_xor(d[j], off, 64);
    }
    const int mk[8] = {mA.x, mA.y, mA.z, mA.w, mB.x, mB.y, mB.z, mB.w};
    float s[8], p[8];
    float mn = m;
#pragma unroll
    for (int j = 0; j < 8; ++j) { s[j] = mk[j] ? -1e30f : d[j]; mn = fmaxf(mn, s[j]); }
    const float scale = __expf(m - mn);   // m starts -1e38 -> scale 0, no NaN
    float psum = 0.f;
#pragma unroll
    for (int j = 0; j < 8; ++j) { p[j] = __expf(s[j] - mn); psum += p[j]; }
    ls = fmaf(ls, scale, psum);
#pragma unroll
    for (int k = 0; k < 4; ++k) {
      float acc0 = c[k] * scale, acc1 = c[4 + k] * scale;
#pragma unroll
      for (int j = 0; j < 8; ++j) {
        acc0 = fmaf(p[j], r[j][0][k], acc0);
        acc1 = fmaf(p[j], r[j][1][k], acc1);
      }
      c[k] = acc0; c[4 + k] = acc1;
    }
    m = mn;
  }

  // ---- combine 8 wave partials within the block via LDS ----
  __shared__ float sc[8][DD];
  __shared__ float sm[8], sl[8];
  float4* dst = reinterpret_cast<float4*>(&sc[wave][lane * 8]);
  dst[0] = make_float4(c[0], c[1], c[2], c[3]);
  dst[1] = make_float4(c[4], c[5], c[6], c[7]);
  if (lane == 0) { sm[wave] = m; sl[wave] = ls; }
  __syncthreads();
  float M = sm[0];
#pragma unroll
  for (int w = 1; w < 8; ++w) M = fmaxf(M, sm[w]);
  float e[8];
#pragma unroll
  for (int w = 0; w < 8; ++w) e[w] = __expf(sm[w] - M);
  float acc = 0.f;
#pragma unroll
  for (int w = 0; w < 8; ++w) acc = fmaf(sc[w][t], e[w], acc);
  pc[(size_t)(b * GG + g) * DD + t] = acc;
  if (t == 0) {
    float L = 0.f;
#pragma unroll
    for (int w = 0; w < 8; ++w) L = fmaf(sl[w], e[w], L);
    pm[b * GG + g] = M;
    pl[b * GG + g] = L;
  }
}

// ---------------- Kernel 2: combine partials + fused dual GEMV + tanh ------
__global__ __launch_bounds__(512) void attn_final(
    const float* __restrict__ pc, const float* __restrict__ pm,
    const float* __restrict__ pl, const float* __restrict__ q,
    const float* __restrict__ Wq, const float* __restrict__ bq,
    const float* __restrict__ Wv, const float* __restrict__ bv,
    float* __restrict__ out) {
  const int b = blockIdx.x >> 2, chunk = blockIdx.x & 3;
  const int t = threadIdx.x;
  __shared__ float ctx[DD], qs[DD];
  float M = -1e38f;
#pragma unroll 8
  for (int g = 0; g < GG; ++g) M = fmaxf(M, pm[b * GG + g]);
  float Ls = 0.f, acc = 0.f;
#pragma unroll 4
  for (int g = 0; g < GG; ++g) {
    const float e = __expf(pm[b * GG + g] - M);
    Ls += pl[b * GG + g] * e;
    acc += pc[(size_t)(b * GG + g) * DD + t] * e;
  }
  ctx[t] = acc / Ls;
  qs[t] = q[b * DD + t];
  __syncthreads();
  const int wave = t >> 6, lane = t & 63;
  float cf[8], qf[8];
#pragma unroll
  for (int j = 0; j < 8; ++j) { cf[j] = ctx[lane * 8 + j]; qf[j] = qs[lane * 8 + j]; }
  const int d0 = chunk * 128;
  for (int d = d0 + wave; d < d0 + 128; d += 8) {
    const float4* wv = reinterpret_cast<const float4*>(Wv + (size_t)d * DD + lane * 8);
    const float4* wq = reinterpret_cast<const float4*>(Wq + (size_t)d * DD + lane * 8);
    float s = dot8(wv[0], wv[1], cf) + dot8(wq[0], wq[1], qf);
#pragma unroll
    for (int off = 32; off >= 1; off >>= 1) s += __shfl_xor(s, off, 64);
    if (lane == 0) out[b * DD + d] = tanhf(s + bv[d] + bq[d]);
  }
}

extern "C" void kernel_launch(void* const* d_in, const int* in_sizes, int n_in,
                              void* d_out, int out_size, void* d_ws, size_t ws_size,
                              hipStream_t stream) {
  const float* query = (const float*)d_in[0];
  const float* value = (const float*)d_in[1];
  const int*   mask  = (const int*)d_in[2];
  const float* Wa    = (const float*)d_in[3];
  const float* ba    = (const float*)d_in[4];
  const float* Wq    = (const float*)d_in[5];
  const float* bq    = (const float*)d_in[6];
  const float* Wv    = (const float*)d_in[7];
  const float* bv    = (const float*)d_in[8];
  float* out = (float*)d_out;

  float* ws = (float*)d_ws;
  float* qbuf = ws;                         // BB*DD    = 8192 floats
  float* pc   = qbuf + BB * DD;             // BB*GG*DD = 524288 floats
  float* pm   = pc + (size_t)BB * GG * DD;  // BB*GG    = 1024 floats
  float* pl   = pm + BB * GG;               // BB*GG    = 1024 floats

  qproj_kernel<<<BB * 4, 512, 0, stream>>>(query, Wa, ba, qbuf);
  attn_pass1<<<BB * GG, 512, 0, stream>>>(value, mask, qbuf, pc, pm, pl);
  attn_final<<<BB * 4, 512, 0, stream>>>(pc, pm, pl, qbuf, Wq, bq, Wv, bv, out);
}

// Round 5
// 392.728 us; speedup vs baseline: 1.0250x; 1.0250x over previous
//
#include <hip/hip_runtime.h>
#include <math.h>

#define BB 16
#define LL 8192
#define DD 512
#define GG 64   // blocks per batch in pass 1 (128 rows each)

typedef float vf4 __attribute__((ext_vector_type(4)));  // clang-native: OK for nontemporal builtins

__device__ __forceinline__ float dot8v(const vf4& x0, const vf4& x1, const float* qf) {
  return x0.x * qf[0] + x0.y * qf[1] + x0.z * qf[2] + x0.w * qf[3]
       + x1.x * qf[4] + x1.y * qf[5] + x1.z * qf[6] + x1.w * qf[7];
}
__device__ __forceinline__ float dot8(const float4& x0, const float4& x1, const float* qf) {
  return x0.x * qf[0] + x0.y * qf[1] + x0.z * qf[2] + x0.w * qf[3]
       + x1.x * qf[4] + x1.y * qf[5] + x1.z * qf[6] + x1.w * qf[7];
}

// ---------------- Kernel 0: q = query @ W_align^T + b_align ----------------
// 64 blocks (16 b x 4 chunks) x 512 threads. Wave-per-output-d, coalesced
// float4 W reads, 64-lane butterfly reduce.
__global__ __launch_bounds__(512) void qproj_kernel(
    const float* __restrict__ query, const float* __restrict__ Wa,
    const float* __restrict__ ba, float* __restrict__ qout) {
  const int b = blockIdx.x >> 2, chunk = blockIdx.x & 3;
  const int t = threadIdx.x;
  __shared__ float qs[DD];
  qs[t] = query[b * DD + t];
  __syncthreads();
  const int wave = t >> 6, lane = t & 63;
  float qf[8];
#pragma unroll
  for (int j = 0; j < 8; ++j) qf[j] = qs[lane * 8 + j];
  const int d0 = chunk * 128;
  for (int d = d0 + wave; d < d0 + 128; d += 8) {
    const float4* wrow = reinterpret_cast<const float4*>(Wa + (size_t)d * DD + lane * 8);
    float s = dot8(wrow[0], wrow[1], qf);
#pragma unroll
    for (int off = 32; off >= 1; off >>= 1) s += __shfl_xor(s, off, 64);
    if (lane == 0) qout[b * DD + d] = ba[d] + s;
  }
}

// ---------------- Kernel 1: online-softmax streaming pass over value -------
// Grid: BB*GG blocks x 512 threads (8 waves). Each wave owns 16 rows,
// processed 2 at a time (interleaved reduces, combined softmax update).
// value is read ONCE, nontemporally. [R4 8-row grouping reverted: regressed
// +8us, suspected VGPR-occupancy step from 16 live vf4 loads.]
__global__ __launch_bounds__(512) void attn_pass1(
    const float* __restrict__ value, const int* __restrict__ mask,
    const float* __restrict__ q, float* __restrict__ pc,
    float* __restrict__ pm, float* __restrict__ pl) {
  const int blk = blockIdx.x;
  const int b = blk / GG, g = blk % GG;
  const int t = threadIdx.x;
  const int wave = t >> 6, lane = t & 63;
  const int l0 = g * 128 + wave * 16;

  float qf[8];
  {
    const float4* qp = reinterpret_cast<const float4*>(q + b * DD + lane * 8);
    float4 q0 = qp[0], q1 = qp[1];
    qf[0] = q0.x; qf[1] = q0.y; qf[2] = q0.z; qf[3] = q0.w;
    qf[4] = q1.x; qf[5] = q1.y; qf[6] = q1.z; qf[7] = q1.w;
  }

  float m = -1e38f, ls = 0.f;
  float c[8] = {0.f, 0.f, 0.f, 0.f, 0.f, 0.f, 0.f, 0.f};
  const float* vb = value + (size_t)b * LL * DD;
  const int* mb = mask + b * LL;

#pragma unroll 2
  for (int i = 0; i < 16; i += 2) {
    const int l = l0 + i;
    const vf4* vp0 = reinterpret_cast<const vf4*>(vb + (size_t)l * DD + lane * 8);
    const vf4* vp1 = reinterpret_cast<const vf4*>(vb + (size_t)(l + 1) * DD + lane * 8);
    // issue all 4 row loads up front (nontemporal: pure stream)
    vf4 a0 = __builtin_nontemporal_load(vp0);
    vf4 a1 = __builtin_nontemporal_load(vp0 + 1);
    vf4 b0 = __builtin_nontemporal_load(vp1);
    vf4 b1 = __builtin_nontemporal_load(vp1 + 1);
    const int mk0 = mb[l], mk1 = mb[l + 1];
    float d0 = dot8v(a0, a1, qf);
    float d1 = dot8v(b0, b1, qf);
    // interleaved butterflies: two independent 6-deep chains overlap
#pragma unroll
    for (int off = 32; off >= 1; off >>= 1) {
      d0 += __shfl_xor(d0, off, 64);
      d1 += __shfl_xor(d1, off, 64);
    }
    const float s0 = mk0 ? -1e30f : d0;   // mask==1 -> masked out (NEG_INF)
    const float s1 = mk1 ? -1e30f : d1;
    const float mn = fmaxf(m, fmaxf(s0, s1));
    const float scale = __expf(m - mn);   // m starts -1e38 -> scale 0, no NaN
    const float p0 = __expf(s0 - mn);
    const float p1 = __expf(s1 - mn);
    ls = fmaf(ls, scale, p0 + p1);
    c[0] = fmaf(p1, b0.x, fmaf(p0, a0.x, c[0] * scale));
    c[1] = fmaf(p1, b0.y, fmaf(p0, a0.y, c[1] * scale));
    c[2] = fmaf(p1, b0.z, fmaf(p0, a0.z, c[2] * scale));
    c[3] = fmaf(p1, b0.w, fmaf(p0, a0.w, c[3] * scale));
    c[4] = fmaf(p1, b1.x, fmaf(p0, a1.x, c[4] * scale));
    c[5] = fmaf(p1, b1.y, fmaf(p0, a1.y, c[5] * scale));
    c[6] = fmaf(p1, b1.z, fmaf(p0, a1.z, c[6] * scale));
    c[7] = fmaf(p1, b1.w, fmaf(p0, a1.w, c[7] * scale));
    m = mn;
  }

  // ---- combine 8 wave partials within the block via LDS ----
  __shared__ float sc[8][DD];
  __shared__ float sm[8], sl[8];
  float4* dst = reinterpret_cast<float4*>(&sc[wave][lane * 8]);
  dst[0] = make_float4(c[0], c[1], c[2], c[3]);
  dst[1] = make_float4(c[4], c[5], c[6], c[7]);
  if (lane == 0) { sm[wave] = m; sl[wave] = ls; }
  __syncthreads();
  float M = sm[0];
#pragma unroll
  for (int w = 1; w < 8; ++w) M = fmaxf(M, sm[w]);
  float e[8];
#pragma unroll
  for (int w = 0; w < 8; ++w) e[w] = __expf(sm[w] - M);
  // one output element per thread: conflict-free LDS column reads
  float acc = 0.f;
#pragma unroll
  for (int w = 0; w < 8; ++w) acc = fmaf(sc[w][t], e[w], acc);
  pc[(size_t)(b * GG + g) * DD + t] = acc;
  if (t == 0) {
    float L = 0.f;
#pragma unroll
    for (int w = 0; w < 8; ++w) L = fmaf(sl[w], e[w], L);
    pm[b * GG + g] = M;
    pl[b * GG + g] = L;
  }
}

// ---------------- Kernel 2: combine partials + fused dual GEMV + tanh ------
// 64 blocks (16 b x 4 chunks) x 512 threads. Combine 64 block-partials ->
// context[512] in LDS, then out[b,d] = tanh(ctx@Wv[d,:]+bv[d]+q@Wq[d,:]+bq[d]).
__global__ __launch_bounds__(512) void attn_final(
    const float* __restrict__ pc, const float* __restrict__ pm,
    const float* __restrict__ pl, const float* __restrict__ q,
    const float* __restrict__ Wq, const float* __restrict__ bq,
    const float* __restrict__ Wv, const float* __restrict__ bv,
    float* __restrict__ out) {
  const int b = blockIdx.x >> 2, chunk = blockIdx.x & 3;
  const int t = threadIdx.x;
  __shared__ float ctx[DD], qs[DD];
  float M = -1e38f;
#pragma unroll 8
  for (int g = 0; g < GG; ++g) M = fmaxf(M, pm[b * GG + g]);
  float Ls = 0.f, acc = 0.f;
#pragma unroll 4
  for (int g = 0; g < GG; ++g) {
    const float e = __expf(pm[b * GG + g] - M);
    Ls += pl[b * GG + g] * e;
    acc += pc[(size_t)(b * GG + g) * DD + t] * e;
  }
  ctx[t] = acc / Ls;
  qs[t] = q[b * DD + t];
  __syncthreads();
  const int wave = t >> 6, lane = t & 63;
  float cf[8], qf[8];
#pragma unroll
  for (int j = 0; j < 8; ++j) { cf[j] = ctx[lane * 8 + j]; qf[j] = qs[lane * 8 + j]; }
  const int d0 = chunk * 128;
  for (int d = d0 + wave; d < d0 + 128; d += 8) {
    const float4* wv = reinterpret_cast<const float4*>(Wv + (size_t)d * DD + lane * 8);
    const float4* wq = reinterpret_cast<const float4*>(Wq + (size_t)d * DD + lane * 8);
    float s = dot8(wv[0], wv[1], cf) + dot8(wq[0], wq[1], qf);
#pragma unroll
    for (int off = 32; off >= 1; off >>= 1) s += __shfl_xor(s, off, 64);
    if (lane == 0) out[b * DD + d] = tanhf(s + bv[d] + bq[d]);
  }
}

extern "C" void kernel_launch(void* const* d_in, const int* in_sizes, int n_in,
                              void* d_out, int out_size, void* d_ws, size_t ws_size,
                              hipStream_t stream) {
  const float* query = (const float*)d_in[0];
  const float* value = (const float*)d_in[1];
  const int*   mask  = (const int*)d_in[2];
  const float* Wa    = (const float*)d_in[3];
  const float* ba    = (const float*)d_in[4];
  const float* Wq    = (const float*)d_in[5];
  const float* bq    = (const float*)d_in[6];
  const float* Wv    = (const float*)d_in[7];
  const float* bv    = (const float*)d_in[8];
  float* out = (float*)d_out;

  float* ws = (float*)d_ws;
  float* qbuf = ws;                         // BB*DD    = 8192 floats
  float* pc   = qbuf + BB * DD;             // BB*GG*DD = 524288 floats
  float* pm   = pc + (size_t)BB * GG * DD;  // BB*GG    = 1024 floats
  float* pl   = pm + BB * GG;               // BB*GG    = 1024 floats

  qproj_kernel<<<BB * 4, 512, 0, stream>>>(query, Wa, ba, qbuf);
  attn_pass1<<<BB * GG, 512, 0, stream>>>(value, mask, qbuf, pc, pm, pl);
  attn_final<<<BB * 4, 512, 0, stream>>>(pc, pm, pl, qbuf, Wq, bq, Wv, bv, out);
}